// Round 13
// baseline (186.887 us; speedup 1.0000x reference)
//
#include <hip/hip_runtime.h>
#include <hip/hip_bf16.h>
#include <cstdint>

typedef __bf16 bf16;
typedef bf16 bf16x8 __attribute__((ext_vector_type(8)));
typedef float f32x4 __attribute__((ext_vector_type(4)));

#define NTOK 4096   // B*T
#define DLBL 512    // D_LABEL
#define NLAB 50

__device__ inline bf16x8 cvt8(float4 a, float4 b) {
  bf16x8 r;
  r[0] = (bf16)a.x; r[1] = (bf16)a.y; r[2] = (bf16)a.z; r[3] = (bf16)a.w;
  r[4] = (bf16)b.x; r[5] = (bf16)b.y; r[6] = (bf16)b.z; r[7] = (bf16)b.w;
  return r;
}

// async global->LDS, 16B per lane; LDS dest = wave-uniform base + lane*16
__device__ __forceinline__ void gl16(const bf16* g, void* l) {
  __builtin_amdgcn_global_load_lds(
      (const __attribute__((address_space(1))) void*)g,
      (__attribute__((address_space(3))) void*)l, 16, 0, 0);
}

// ---------------------------------------------------------------------------
// Prep: blocks [0,256) projA (transposed out), [256,512) projB (gathered).
// convW is GONE -- biaff now stages W f32 directly (saves the 157MB pass).
// ---------------------------------------------------------------------------
__device__ void projA_body(int bidx, const float* __restrict__ Wp,
                           const float* __restrict__ X,
                           const float* __restrict__ bv,
                           bf16* __restrict__ outT, char* lds) {
  char* ldsA = lds;           // [128 e][32 d] bf16, row stride 80B
  char* ldsB = lds + 10240;   // [64 tok][32 d] bf16, row stride 80B
  const int tid = threadIdx.x, l = tid & 63, w = tid >> 6;
  const int tokbase = (bidx >> 2) * 64;
  const int ebase   = (bidx & 3) * 128;
  const int wr = w & 1, wc = w >> 1;
  f32x4 acc[4][2] = {};
  const int arow = tid >> 1, ahalf = tid & 1;
  const int brow = tid >> 2, bgr = tid & 3;
  const float* aS = Wp + (size_t)(ebase + arow) * 1024 + ahalf * 16;
  const float* bS = X  + (size_t)(tokbase + brow) * 1024 + bgr * 8;
  const int lo = (l & 15) * 80 + (l >> 4) * 16;
  for (int kb = 0; kb < 1024; kb += 32) {
    float4 a0 = *(const float4*)(aS + kb);
    float4 a1 = *(const float4*)(aS + kb + 4);
    float4 a2 = *(const float4*)(aS + kb + 8);
    float4 a3 = *(const float4*)(aS + kb + 12);
    float4 b0 = *(const float4*)(bS + kb);
    float4 b1 = *(const float4*)(bS + kb + 4);
    *(bf16x8*)(ldsA + arow * 80 + ahalf * 32)      = cvt8(a0, a1);
    *(bf16x8*)(ldsA + arow * 80 + ahalf * 32 + 16) = cvt8(a2, a3);
    *(bf16x8*)(ldsB + brow * 80 + bgr * 16)        = cvt8(b0, b1);
    __syncthreads();
    bf16x8 aF[4], bF[2];
#pragma unroll
    for (int i = 0; i < 4; ++i) aF[i] = *(bf16x8*)(ldsA + (wr * 64 + i * 16) * 80 + lo);
#pragma unroll
    for (int j = 0; j < 2; ++j) bF[j] = *(bf16x8*)(ldsB + (wc * 32 + j * 16) * 80 + lo);
#pragma unroll
    for (int i = 0; i < 4; ++i)
#pragma unroll
      for (int j = 0; j < 2; ++j)
        acc[i][j] = __builtin_amdgcn_mfma_f32_16x16x32_bf16(aF[i], bF[j], acc[i][j], 0, 0, 0);
    __syncthreads();
  }
#pragma unroll
  for (int i = 0; i < 4; ++i)
#pragma unroll
    for (int j = 0; j < 2; ++j)
#pragma unroll
      for (int r = 0; r < 4; ++r) {
        int eg = ebase + wr * 64 + i * 16 + (l >> 4) * 4 + r;
        int tg = tokbase + wc * 32 + j * 16 + (l & 15);
        outT[(size_t)eg * NTOK + tg] = (bf16)(acc[i][j][r] + bv[eg]);
      }
}

__device__ void projB_body(int bidx, const float* __restrict__ head,
                           const int* __restrict__ hidx,
                           const float* __restrict__ Wp,
                           const float* __restrict__ bv,
                           bf16* __restrict__ selO, char* lds) {
  char* ldsA = lds;           // [128 tok][32 d], stride 80
  char* ldsB = lds + 10240;   // [64 e][32 d], stride 80
  const int tid = threadIdx.x, l = tid & 63, w = tid >> 6;
  const int tokbase = (bidx >> 3) * 128;
  const int ebase   = (bidx & 7) * 64;
  const int wr = w & 1, wc = w >> 1;
  f32x4 acc[4][2] = {};
  const int arow = tid >> 1, ahalf = tid & 1;
  const int brow = tid >> 2, bgr = tid & 3;
  const int flat = tokbase + arow;
  const int bb = flat >> 11;
  const int hv = hidx[flat];
  const float* aS = head + ((size_t)bb * 2049 + hv) * 1024 + ahalf * 16;
  const float* bS = Wp + (size_t)(ebase + brow) * 1024 + bgr * 8;
  const int lo = (l & 15) * 80 + (l >> 4) * 16;
  for (int kb = 0; kb < 1024; kb += 32) {
    float4 a0 = *(const float4*)(aS + kb);
    float4 a1 = *(const float4*)(aS + kb + 4);
    float4 a2 = *(const float4*)(aS + kb + 8);
    float4 a3 = *(const float4*)(aS + kb + 12);
    float4 b0 = *(const float4*)(bS + kb);
    float4 b1 = *(const float4*)(bS + kb + 4);
    *(bf16x8*)(ldsA + arow * 80 + ahalf * 32)      = cvt8(a0, a1);
    *(bf16x8*)(ldsA + arow * 80 + ahalf * 32 + 16) = cvt8(a2, a3);
    *(bf16x8*)(ldsB + brow * 80 + bgr * 16)        = cvt8(b0, b1);
    __syncthreads();
    bf16x8 aF[4], bF[2];
#pragma unroll
    for (int i = 0; i < 4; ++i) aF[i] = *(bf16x8*)(ldsA + (wr * 64 + i * 16) * 80 + lo);
#pragma unroll
    for (int j = 0; j < 2; ++j) bF[j] = *(bf16x8*)(ldsB + (wc * 32 + j * 16) * 80 + lo);
#pragma unroll
    for (int i = 0; i < 4; ++i)
#pragma unroll
      for (int j = 0; j < 2; ++j)
        acc[i][j] = __builtin_amdgcn_mfma_f32_16x16x32_bf16(aF[i], bF[j], acc[i][j], 0, 0, 0);
    __syncthreads();
  }
#pragma unroll
  for (int i = 0; i < 4; ++i)
#pragma unroll
    for (int j = 0; j < 2; ++j)
#pragma unroll
      for (int r = 0; r < 4; ++r) {
        int tg = tokbase + wr * 64 + i * 16 + (l >> 4) * 4 + r;
        int eg = ebase + wc * 32 + j * 16 + (l & 15);
        selO[(size_t)tg * DLBL + eg] = (bf16)(acc[i][j][r] + bv[eg]);
      }
}

__global__ __launch_bounds__(256) void prep_k(const float* __restrict__ dep_W,
                                              const float* __restrict__ dep,
                                              const float* __restrict__ dep_b,
                                              bf16* __restrict__ depT,
                                              const float* __restrict__ head,
                                              const int* __restrict__ hidx,
                                              const float* __restrict__ head_W,
                                              const float* __restrict__ head_b,
                                              bf16* __restrict__ selB) {
  __shared__ char lds[15360];
  const int b = blockIdx.x;
  if (b < 256) projA_body(b, dep_W, dep, dep_b, depT, lds);
  else         projB_body(b - 256, head, hidx, head_W, head_b, selB, lds);
}

// ---------------------------------------------------------------------------
// Kernel biaff v13: r5's proven loop, but A staged from W *f32* via
// reg-staging (global_load f32 -> cvt -> ds_write, same swizzled image);
// B stays gl16. Pipeline: A(u) loaded phase u-3 (2x float4/thread),
// cvt+ds_write phase u-1 -> buf u%3, read phase u. Per phase: 2 gl16-B +
// 2 A-loads = 4 vm ops; vmcnt(4)/phase certifies prev phase's B AND A-regs
// (FIFO); lgkmcnt(0) before barrier makes A ds_writes cross-wave visible.
// ds_reads remain FIRST in phase (r9/r10 lesson). Tail: vmcnt 2 then 0.
// ---------------------------------------------------------------------------
__global__ __launch_bounds__(512, 4) void biaff_k(const float* __restrict__ Wf,
                                                  const bf16* __restrict__ sel,
                                                  const bf16* __restrict__ depT,
                                                  float* __restrict__ parts) {
  __shared__ char lds[73728];          // 3 x (A 8KB + B 16KB)
  const int tid = threadIdx.x, l = tid & 63, w = tid >> 6;

  // bijective XCD-aware decode: combo fast, tok slow (r5-proven)
  const int lin = blockIdx.x;
  const int xcd = lin & 7, idx = lin >> 3;
  const int sub = idx % 25;
  const int bx  = idx / 25;
  const int combo = xcd * 25 + sub;
  const int n  = combo % 50;
  const int dz = combo / 50;
  const int tokbase = bx * 256;
  const int dbase   = dz * 128;

  const int wd = w >> 2, wt = w & 3;   // wave tile: 64 d x 64 tok
  f32x4 acc[4][4] = {};

  const int srow = l >> 2;
  const int schunk = ((l & 3) ^ ((l >> 3) & 3)) * 8;
  // A source: W f32, same row/chunk mapping as the old bf16 gl16 path
  const float* aGf = Wf + ((size_t)(n * DLBL + dbase + w * 16 + srow)) * DLBL + schunk;
  const bf16*  bG  = sel + ((size_t)(tokbase + w * 32 + srow)) * DLBL + schunk;
  char* wrA = lds + w * 1024 + l * 16;          // A write addr (linear image)
  const int bOff = 8192 + w * 2048;

  const int lq = l & 15, lh = l >> 4;
  const int ro = lh ^ ((lq >> 1) & 3);
  const char* rdA = lds + (wd * 64 + lq) * 64 + ro * 16;
  const char* rdB = lds + 8192 + (wt * 64 + lq) * 64 + ro * 16;

  float4 rsa, rsb, rta, rtb;   // two A reg sets (static names, no dyn index)

#define WAITV(N) asm volatile("s_waitcnt vmcnt(" #N ")" ::: "memory")
#define WAITL    asm volatile("s_waitcnt lgkmcnt(0)" ::: "memory")
#define STGB(T) do { \
    const bf16* b_ = bG + (T) * 32; \
    char* lb_ = lds + ((T) % 3) * 24576 + bOff; \
    gl16(b_, lb_); \
    gl16(b_ + 16 * DLBL, lb_ + 1024); \
  } while (0)
#define LDA(T, Ra, Rb) do { \
    const float4* p_ = (const float4*)(aGf + (T) * 32); \
    Ra = p_[0]; Rb = p_[1]; \
  } while (0)
// PHASE: ds_read tile T | cvt+write A(T+1) | gl16 B(T+2) | load A(T+3) | MFMA
#define PHASE(T, Ra, Rb, DOCVT, DOB, DOA, DOW4, DOW2, DOW0, DOBAR) do { \
    const char* cA = rdA + ((T) % 3) * 24576; \
    const char* cB = rdB + ((T) % 3) * 24576; \
    bf16x8 aF[4], bF[4]; \
    aF[0] = *(const bf16x8*)(cA + 0 * 1024); \
    aF[1] = *(const bf16x8*)(cA + 1 * 1024); \
    aF[2] = *(const bf16x8*)(cA + 2 * 1024); \
    aF[3] = *(const bf16x8*)(cA + 3 * 1024); \
    bF[0] = *(const bf16x8*)(cB + 0 * 1024); \
    bF[1] = *(const bf16x8*)(cB + 1 * 1024); \
    bF[2] = *(const bf16x8*)(cB + 2 * 1024); \
    bF[3] = *(const bf16x8*)(cB + 3 * 1024); \
    if (DOCVT) *(bf16x8*)(wrA + (((T) + 1) % 3) * 24576) = cvt8(Ra, Rb); \
    if (DOB) STGB((T) + 2); \
    if (DOA) LDA((T) + 3, Ra, Rb); \
    __builtin_amdgcn_s_setprio(1); \
    _Pragma("unroll") \
    for (int i = 0; i < 4; ++i) \
      _Pragma("unroll") \
      for (int j = 0; j < 4; ++j) \
        acc[i][j] = __builtin_amdgcn_mfma_f32_16x16x32_bf16(aF[i], bF[j], acc[i][j], 0, 0, 0); \
    __builtin_amdgcn_s_setprio(0); \
    if (DOW4) WAITV(4); \
    if (DOW2) WAITV(2); \
    if (DOW0) WAITV(0); \
    if (DOBAR) { WAITL; __builtin_amdgcn_s_barrier(); } \
  } while (0)

  // ---- prologue: A0 -> LDS buf0; A1 -> set t; A2 -> set s; B0, B1 ----
  LDA(0, rsa, rsb);
  WAITV(0);
  *(bf16x8*)(wrA) = cvt8(rsa, rsb);            // buf 0 A-region
  LDA(2, rsa, rsb);                             // set s <- A2 (cvt in phase 1)
  LDA(1, rta, rtb);                             // set t <- A1 (cvt in phase 0)
  STGB(0); STGB(1);
  WAITV(2);                                     // A2, A1, B0 done; B1 in flight
  WAITL;
  __builtin_amdgcn_s_barrier();

  PHASE(0,  rta, rtb, 1, 1, 1, 1, 0, 0, 1);
  PHASE(1,  rsa, rsb, 1, 1, 1, 1, 0, 0, 1);
  PHASE(2,  rta, rtb, 1, 1, 1, 1, 0, 0, 1);
  PHASE(3,  rsa, rsb, 1, 1, 1, 1, 0, 0, 1);
  PHASE(4,  rta, rtb, 1, 1, 1, 1, 0, 0, 1);
  PHASE(5,  rsa, rsb, 1, 1, 1, 1, 0, 0, 1);
  PHASE(6,  rta, rtb, 1, 1, 1, 1, 0, 0, 1);
  PHASE(7,  rsa, rsb, 1, 1, 1, 1, 0, 0, 1);
  PHASE(8,  rta, rtb, 1, 1, 1, 1, 0, 0, 1);
  PHASE(9,  rsa, rsb, 1, 1, 1, 1, 0, 0, 1);
  PHASE(10, rta, rtb, 1, 1, 1, 1, 0, 0, 1);
  PHASE(11, rsa, rsb, 1, 1, 1, 1, 0, 0, 1);
  PHASE(12, rta, rtb, 1, 1, 1, 1, 0, 0, 1);   // last A-load (A15 -> set t)
  PHASE(13, rsa, rsb, 1, 1, 0, 0, 1, 0, 1);   // cvt A14; stage B15; vmcnt(2)
  PHASE(14, rta, rtb, 1, 0, 0, 0, 0, 1, 1);   // cvt A15; vmcnt(0)
  PHASE(15, rta, rtb, 0, 0, 0, 0, 0, 0, 0);   // final tile

#undef PHASE
#undef LDA
#undef STGB
#undef WAITL
#undef WAITV

  // ---- epilogue: H[d,t] * depT[d,t], reduce over the wave's 64 d ----
  float p[4] = {0.f, 0.f, 0.f, 0.f};
#pragma unroll
  for (int j = 0; j < 4; ++j) {
    const int tg = tokbase + wt * 64 + j * 16 + lq;
#pragma unroll
    for (int i = 0; i < 4; ++i)
#pragma unroll
      for (int r = 0; r < 4; ++r) {
        int dg = dbase + wd * 64 + i * 16 + lh * 4 + r;
        p[j] += acc[i][j][r] * (float)depT[(size_t)dg * NTOK + tg];
      }
  }
#pragma unroll
  for (int j = 0; j < 4; ++j) {
    p[j] += __shfl_xor(p[j], 16);
    p[j] += __shfl_xor(p[j], 32);
  }
  if (l < 16) {
#pragma unroll
    for (int j = 0; j < 4; ++j) {
      int tg = tokbase + wt * 64 + j * 16 + l;
      parts[(size_t)(dz * 2 + wd) * 204800 + (size_t)tg * NLAB + n] = p[j];
    }
  }
}

// ---------------------------------------------------------------------------
// Kernel: sum the 8 d-partials + bias -> logits [4096][50] f32
// ---------------------------------------------------------------------------
__global__ __launch_bounds__(256) void fin_k(const float* __restrict__ parts,
                                             const float* __restrict__ bias,
                                             float* __restrict__ out) {
  int i = blockIdx.x * 256 + threadIdx.x;
  float v = 0.f;
#pragma unroll
  for (int q = 0; q < 8; ++q) v += parts[(size_t)q * 204800 + i];
  out[i] = v + bias[i % NLAB];
}

// ---------------------------------------------------------------------------
extern "C" void kernel_launch(void* const* d_in, const int* in_sizes, int n_in,
                              void* d_out, int out_size, void* d_ws, size_t ws_size,
                              hipStream_t stream) {
  const float* dep    = (const float*)d_in[0];
  const float* head   = (const float*)d_in[1];
  const int*   hidx   = (const int*)d_in[2];
  const float* dep_W  = (const float*)d_in[4];
  const float* dep_b  = (const float*)d_in[5];
  const float* head_W = (const float*)d_in[6];
  const float* head_b = (const float*)d_in[7];
  const float* W      = (const float*)d_in[8];
  const float* bias   = (const float*)d_in[9];
  float* out = (float*)d_out;

  char* ws = (char*)d_ws;
  bf16*  depT  = (bf16*)(ws);                // 4,194,304 B
  bf16*  selB  = (bf16*)(ws + 4194304);      // 4,194,304 B
  float* parts = (float*)(ws + 8388608);     // 8 * 204800 * 4 = 6,553,600 B
  if (ws_size < (size_t)14942208) return;

  hipLaunchKernelGGL(prep_k, dim3(512), dim3(256), 0, stream,
                     dep_W, dep, dep_b, depT, head, hidx, head_W, head_b, selB);
  hipLaunchKernelGGL(biaff_k, dim3(3200), dim3(512), 0, stream,
                     W, selB, depT, parts);
  hipLaunchKernelGGL(fin_k, dim3(800), dim3(256), 0, stream, parts, bias, out);
}

// Round 14
// 165.488 us; speedup vs baseline: 1.1293x; 1.1293x over previous
//
#include <hip/hip_runtime.h>
#include <hip/hip_bf16.h>
#include <cstdint>

typedef __bf16 bf16;
typedef bf16 bf16x8 __attribute__((ext_vector_type(8)));
typedef float f32x4 __attribute__((ext_vector_type(4)));

#define NTOK 4096   // B*T
#define DLBL 512    // D_LABEL
#define NLAB 50

__device__ inline bf16x8 cvt8(float4 a, float4 b) {
  bf16x8 r;
  r[0] = (bf16)a.x; r[1] = (bf16)a.y; r[2] = (bf16)a.z; r[3] = (bf16)a.w;
  r[4] = (bf16)b.x; r[5] = (bf16)b.y; r[6] = (bf16)b.z; r[7] = (bf16)b.w;
  return r;
}

// async global->LDS, 16B per lane; LDS dest = wave-uniform base + lane*16
__device__ __forceinline__ void gl16(const bf16* g, void* l) {
  __builtin_amdgcn_global_load_lds(
      (const __attribute__((address_space(1))) void*)g,
      (__attribute__((address_space(3))) void*)l, 16, 0, 0);
}

// ---------------------------------------------------------------------------
// Fused prep (r6-proven): blocks [0,256) projA (transposed out),
// [256,512) projB (gathered, natural out), [512,6912) convW.
// convW is NOT waste: Wb bf16 keeps biaff's per-XCD W slice at 3.2MB (<4MB
// L2); staging W f32 directly (r13) thrashed L2 (6.4MB slice, FETCH 2x).
// ---------------------------------------------------------------------------
__device__ void projA_body(int bidx, const float* __restrict__ Wp,
                           const float* __restrict__ X,
                           const float* __restrict__ bv,
                           bf16* __restrict__ outT, char* lds) {
  char* ldsA = lds;           // [128 e][32 d] bf16, row stride 80B
  char* ldsB = lds + 10240;   // [64 tok][32 d] bf16, row stride 80B
  const int tid = threadIdx.x, l = tid & 63, w = tid >> 6;
  const int tokbase = (bidx >> 2) * 64;
  const int ebase   = (bidx & 3) * 128;
  const int wr = w & 1, wc = w >> 1;
  f32x4 acc[4][2] = {};
  const int arow = tid >> 1, ahalf = tid & 1;
  const int brow = tid >> 2, bgr = tid & 3;
  const float* aS = Wp + (size_t)(ebase + arow) * 1024 + ahalf * 16;
  const float* bS = X  + (size_t)(tokbase + brow) * 1024 + bgr * 8;
  const int lo = (l & 15) * 80 + (l >> 4) * 16;
  for (int kb = 0; kb < 1024; kb += 32) {
    float4 a0 = *(const float4*)(aS + kb);
    float4 a1 = *(const float4*)(aS + kb + 4);
    float4 a2 = *(const float4*)(aS + kb + 8);
    float4 a3 = *(const float4*)(aS + kb + 12);
    float4 b0 = *(const float4*)(bS + kb);
    float4 b1 = *(const float4*)(bS + kb + 4);
    *(bf16x8*)(ldsA + arow * 80 + ahalf * 32)      = cvt8(a0, a1);
    *(bf16x8*)(ldsA + arow * 80 + ahalf * 32 + 16) = cvt8(a2, a3);
    *(bf16x8*)(ldsB + brow * 80 + bgr * 16)        = cvt8(b0, b1);
    __syncthreads();
    bf16x8 aF[4], bF[2];
#pragma unroll
    for (int i = 0; i < 4; ++i) aF[i] = *(bf16x8*)(ldsA + (wr * 64 + i * 16) * 80 + lo);
#pragma unroll
    for (int j = 0; j < 2; ++j) bF[j] = *(bf16x8*)(ldsB + (wc * 32 + j * 16) * 80 + lo);
#pragma unroll
    for (int i = 0; i < 4; ++i)
#pragma unroll
      for (int j = 0; j < 2; ++j)
        acc[i][j] = __builtin_amdgcn_mfma_f32_16x16x32_bf16(aF[i], bF[j], acc[i][j], 0, 0, 0);
    __syncthreads();
  }
#pragma unroll
  for (int i = 0; i < 4; ++i)
#pragma unroll
    for (int j = 0; j < 2; ++j)
#pragma unroll
      for (int r = 0; r < 4; ++r) {
        int eg = ebase + wr * 64 + i * 16 + (l >> 4) * 4 + r;
        int tg = tokbase + wc * 32 + j * 16 + (l & 15);
        outT[(size_t)eg * NTOK + tg] = (bf16)(acc[i][j][r] + bv[eg]);
      }
}

__device__ void projB_body(int bidx, const float* __restrict__ head,
                           const int* __restrict__ hidx,
                           const float* __restrict__ Wp,
                           const float* __restrict__ bv,
                           bf16* __restrict__ selO, char* lds) {
  char* ldsA = lds;           // [128 tok][32 d], stride 80
  char* ldsB = lds + 10240;   // [64 e][32 d], stride 80
  const int tid = threadIdx.x, l = tid & 63, w = tid >> 6;
  const int tokbase = (bidx >> 3) * 128;
  const int ebase   = (bidx & 7) * 64;
  const int wr = w & 1, wc = w >> 1;
  f32x4 acc[4][2] = {};
  const int arow = tid >> 1, ahalf = tid & 1;
  const int brow = tid >> 2, bgr = tid & 3;
  const int flat = tokbase + arow;
  const int bb = flat >> 11;
  const int hv = hidx[flat];
  const float* aS = head + ((size_t)bb * 2049 + hv) * 1024 + ahalf * 16;
  const float* bS = Wp + (size_t)(ebase + brow) * 1024 + bgr * 8;
  const int lo = (l & 15) * 80 + (l >> 4) * 16;
  for (int kb = 0; kb < 1024; kb += 32) {
    float4 a0 = *(const float4*)(aS + kb);
    float4 a1 = *(const float4*)(aS + kb + 4);
    float4 a2 = *(const float4*)(aS + kb + 8);
    float4 a3 = *(const float4*)(aS + kb + 12);
    float4 b0 = *(const float4*)(bS + kb);
    float4 b1 = *(const float4*)(bS + kb + 4);
    *(bf16x8*)(ldsA + arow * 80 + ahalf * 32)      = cvt8(a0, a1);
    *(bf16x8*)(ldsA + arow * 80 + ahalf * 32 + 16) = cvt8(a2, a3);
    *(bf16x8*)(ldsB + brow * 80 + bgr * 16)        = cvt8(b0, b1);
    __syncthreads();
    bf16x8 aF[4], bF[2];
#pragma unroll
    for (int i = 0; i < 4; ++i) aF[i] = *(bf16x8*)(ldsA + (wr * 64 + i * 16) * 80 + lo);
#pragma unroll
    for (int j = 0; j < 2; ++j) bF[j] = *(bf16x8*)(ldsB + (wc * 32 + j * 16) * 80 + lo);
#pragma unroll
    for (int i = 0; i < 4; ++i)
#pragma unroll
      for (int j = 0; j < 2; ++j)
        acc[i][j] = __builtin_amdgcn_mfma_f32_16x16x32_bf16(aF[i], bF[j], acc[i][j], 0, 0, 0);
    __syncthreads();
  }
#pragma unroll
  for (int i = 0; i < 4; ++i)
#pragma unroll
    for (int j = 0; j < 2; ++j)
#pragma unroll
      for (int r = 0; r < 4; ++r) {
        int tg = tokbase + wr * 64 + i * 16 + (l >> 4) * 4 + r;
        int eg = ebase + wc * 32 + j * 16 + (l & 15);
        selO[(size_t)tg * DLBL + eg] = (bf16)(acc[i][j][r] + bv[eg]);
      }
}

__global__ __launch_bounds__(256) void prep_k(const float* __restrict__ W,
                                              bf16* __restrict__ Wb,
                                              const float* __restrict__ dep_W,
                                              const float* __restrict__ dep,
                                              const float* __restrict__ dep_b,
                                              bf16* __restrict__ depT,
                                              const float* __restrict__ head,
                                              const int* __restrict__ hidx,
                                              const float* __restrict__ head_W,
                                              const float* __restrict__ head_b,
                                              bf16* __restrict__ selB) {
  __shared__ char lds[15360];
  const int b = blockIdx.x;
  if (b < 256) {
    projA_body(b, dep_W, dep, dep_b, depT, lds);
  } else if (b < 512) {
    projB_body(b - 256, head, hidx, head_W, head_b, selB, lds);
  } else {
    int i = (b - 512) * 256 + threadIdx.x;
    const float4* s = (const float4*)W + (size_t)i * 2;
    float4 a = s[0], c = s[1];
    *(bf16x8*)(Wb + (size_t)i * 8) = cvt8(a, c);
  }
}

// ---------------------------------------------------------------------------
// Kernel 4 == r5/r12 VERBATIM (125.6us, MfmaUtil 38, Occ 39, reproduced 3x):
// 128d x 256tok, 16x16x32, BK=32, 3-buffer 72KB LDS, 2 blocks/CU via
// __launch_bounds__(512,4), ds_read FIRST then STG(t+2) then MFMA, counted
// vmcnt(3), 1 barrier/K-tile, setprio. Shfl-only epilogue, 8 parts slices.
// ---------------------------------------------------------------------------
__global__ __launch_bounds__(512, 4) void biaff_k(const bf16* __restrict__ Wb,
                                                  const bf16* __restrict__ sel,
                                                  const bf16* __restrict__ depT,
                                                  float* __restrict__ parts) {
  __shared__ char lds[73728];          // 3 x (A 8KB + B 16KB)
  const int tid = threadIdx.x, l = tid & 63, w = tid >> 6;

  // bijective XCD-aware decode: combo fast, tok slow (r5-proven)
  const int lin = blockIdx.x;
  const int xcd = lin & 7, idx = lin >> 3;   // idx 0..399
  const int sub = idx % 25;
  const int bx  = idx / 25;                  // tok tile 0..15
  const int combo = xcd * 25 + sub;          // 0..199
  const int n  = combo % 50;
  const int dz = combo / 50;                 // 0..3
  const int tokbase = bx * 256;
  const int dbase   = dz * 128;

  const int wd = w >> 2, wt = w & 3;         // wave tile: 64 d x 64 tok
  f32x4 acc[4][4] = {};

  const int srow = l >> 2;
  const int schunk = ((l & 3) ^ ((l >> 3) & 3)) * 8;
  const bf16* aG = Wb  + ((size_t)(n * DLBL + dbase + w * 16 + srow)) * DLBL + schunk;
  const bf16* bG = sel + ((size_t)(tokbase + w * 32 + srow)) * DLBL + schunk;
  const int aOff = w * 1024;                 // w*16 rows * 64B
  const int bOff = 8192 + w * 2048;          // w*32 rows * 64B

  const int lq = l & 15, lh = l >> 4;
  const int ro = lh ^ ((lq >> 1) & 3);
  const char* rdA = lds + (wd * 64 + lq) * 64 + ro * 16;
  const char* rdB = lds + 8192 + (wt * 64 + lq) * 64 + ro * 16;

#define STG(T) do { \
    const bf16* a_ = aG + (T) * 32; \
    const bf16* b_ = bG + (T) * 32; \
    char* la_ = lds + ((T) % 3) * 24576 + aOff; \
    char* lb_ = lds + ((T) % 3) * 24576 + bOff; \
    gl16(a_, la_); \
    gl16(b_, lb_); \
    gl16(b_ + 16 * DLBL, lb_ + 1024); \
  } while (0)
#define WAITV(N) asm volatile("s_waitcnt vmcnt(" #N ")" ::: "memory")
#define PHASE(T, DOSTG, DOWV3, DOWV0, DOBAR) do { \
    const char* cA = rdA + ((T) % 3) * 24576; \
    const char* cB = rdB + ((T) % 3) * 24576; \
    bf16x8 aF[4], bF[4]; \
    aF[0] = *(const bf16x8*)(cA + 0 * 1024); \
    aF[1] = *(const bf16x8*)(cA + 1 * 1024); \
    aF[2] = *(const bf16x8*)(cA + 2 * 1024); \
    aF[3] = *(const bf16x8*)(cA + 3 * 1024); \
    bF[0] = *(const bf16x8*)(cB + 0 * 1024); \
    bF[1] = *(const bf16x8*)(cB + 1 * 1024); \
    bF[2] = *(const bf16x8*)(cB + 2 * 1024); \
    bF[3] = *(const bf16x8*)(cB + 3 * 1024); \
    if (DOSTG) STG((T) + 2); \
    __builtin_amdgcn_s_setprio(1); \
    _Pragma("unroll") \
    for (int i = 0; i < 4; ++i) \
      _Pragma("unroll") \
      for (int j = 0; j < 4; ++j) \
        acc[i][j] = __builtin_amdgcn_mfma_f32_16x16x32_bf16(aF[i], bF[j], acc[i][j], 0, 0, 0); \
    __builtin_amdgcn_s_setprio(0); \
    if (DOWV3) WAITV(3); \
    if (DOWV0) WAITV(0); \
    if (DOBAR) __builtin_amdgcn_s_barrier(); \
  } while (0)

  // prologue: stage tiles 0,1 (6 loads/wave); certify tile 0 (drain to 3)
  STG(0); STG(1);
  WAITV(3);
  __builtin_amdgcn_s_barrier();

  PHASE(0, 1, 1, 0, 1);  PHASE(1, 1, 1, 0, 1);  PHASE(2, 1, 1, 0, 1);
  PHASE(3, 1, 1, 0, 1);  PHASE(4, 1, 1, 0, 1);  PHASE(5, 1, 1, 0, 1);
  PHASE(6, 1, 1, 0, 1);  PHASE(7, 1, 1, 0, 1);  PHASE(8, 1, 1, 0, 1);
  PHASE(9, 1, 1, 0, 1);  PHASE(10, 1, 1, 0, 1); PHASE(11, 1, 1, 0, 1);
  PHASE(12, 1, 1, 0, 1); PHASE(13, 1, 1, 0, 1);
  PHASE(14, 0, 0, 1, 1);                      // no stage; certify tile 15
  PHASE(15, 0, 0, 0, 0);                      // final tile, no sync needed

#undef PHASE
#undef WAITV
#undef STG

  // ---- epilogue: H[d,t] * depT[d,t], reduce over the wave's 64 d ----
  float p[4] = {0.f, 0.f, 0.f, 0.f};
#pragma unroll
  for (int j = 0; j < 4; ++j) {
    const int tg = tokbase + wt * 64 + j * 16 + lq;
#pragma unroll
    for (int i = 0; i < 4; ++i)
#pragma unroll
      for (int r = 0; r < 4; ++r) {
        int dg = dbase + wd * 64 + i * 16 + lh * 4 + r;
        p[j] += acc[i][j][r] * (float)depT[(size_t)dg * NTOK + tg];
      }
  }
#pragma unroll
  for (int j = 0; j < 4; ++j) {
    p[j] += __shfl_xor(p[j], 16);
    p[j] += __shfl_xor(p[j], 32);
  }
  if (l < 16) {
#pragma unroll
    for (int j = 0; j < 4; ++j) {
      int tg = tokbase + wt * 64 + j * 16 + l;
      parts[(size_t)(dz * 2 + wd) * 204800 + (size_t)tg * NLAB + n] = p[j];
    }
  }
}

// ---------------------------------------------------------------------------
// Kernel 5: sum the 8 d-partials + bias -> logits [4096][50] f32
// ---------------------------------------------------------------------------
__global__ __launch_bounds__(256) void fin_k(const float* __restrict__ parts,
                                             const float* __restrict__ bias,
                                             float* __restrict__ out) {
  int i = blockIdx.x * 256 + threadIdx.x;
  float v = 0.f;
#pragma unroll
  for (int q = 0; q < 8; ++q) v += parts[(size_t)q * 204800 + i];
  out[i] = v + bias[i % NLAB];
}

// ---------------------------------------------------------------------------
extern "C" void kernel_launch(void* const* d_in, const int* in_sizes, int n_in,
                              void* d_out, int out_size, void* d_ws, size_t ws_size,
                              hipStream_t stream) {
  const float* dep    = (const float*)d_in[0];
  const float* head   = (const float*)d_in[1];
  const int*   hidx   = (const int*)d_in[2];
  const float* dep_W  = (const float*)d_in[4];
  const float* dep_b  = (const float*)d_in[5];
  const float* head_W = (const float*)d_in[6];
  const float* head_b = (const float*)d_in[7];
  const float* W      = (const float*)d_in[8];
  const float* bias   = (const float*)d_in[9];
  float* out = (float*)d_out;

  char* ws = (char*)d_ws;
  bf16*  Wb    = (bf16*)(ws);
  bf16*  depT  = (bf16*)(ws + 26214400);
  bf16*  selB  = (bf16*)(ws + 30408704);
  float* parts = (float*)(ws + 34603008);   // 8 * 204800 f32
  if (ws_size < (size_t)41156608) return;

  hipLaunchKernelGGL(prep_k, dim3(6912), dim3(256), 0, stream,
                     W, Wb, dep_W, dep, dep_b, depT, head, hidx, head_W, head_b, selB);
  hipLaunchKernelGGL(biaff_k, dim3(3200), dim3(512), 0, stream,
                     Wb, selB, depT, parts);
  hipLaunchKernelGGL(fin_k, dim3(800), dim3(256), 0, stream, parts, bias, out);
}